// Round 12
// baseline (439.838 us; speedup 1.0000x reference)
//
#include <hip/hip_runtime.h>

#define B_ 64
#define T_ 2000
#define V_ 512
#define L_ 200
#define NJB 16   // j-blocks per batch in kprob: 16 blocks x 4 waves = 64 slots/batch
#define NCH 250  // max chunks per batch

// Two-phase CTC, zero inter-block sync. Round-12: kprob rewrite.
// Round-11 kprob cost ~75us vs 43us per-CU BW floor; mechanism: 8 serialized
// LDS round-trip waits per chunk (write row -> lgkmcnt(0) -> gather) and one
// chunk per wave (4032 launches/COMPACTs). Now: each wave owns 3-4 chunks
// (slot, slot+64, slot+128[, slot+192]), double-buffered X registers (next
// chunk's 16 loads issued before processing current), batched LDS (all 8 rows
// written, ONE lgkmcnt(0), then all gathers), launch_bounds(256,2).
// krec/kcomb byte-identical to the round-11-verified versions.

typedef _Float16 half4 __attribute__((ext_vector_type(4)));
typedef unsigned long long ull;
typedef ull u64x2 __attribute__((ext_vector_type(2)));
union H4U { unsigned long long u; half4 h; };

__device__ __forceinline__ float dpp_shr1_f(float x) {  // lane i <- lane i-1; lane0 <- 0
  return __int_as_float(__builtin_amdgcn_update_dpp(0, __float_as_int(x), 0x138, 0xf, 0xf, true));
}
__device__ __forceinline__ int dpp_shr1_i(int x) {
  return __builtin_amdgcn_update_dpp(0, x, 0x138, 0xf, 0xf, true);
}
__device__ __forceinline__ float dpp_shl1_f(float x) {  // lane i <- lane i+1; lane63 <- 0
  return __int_as_float(__builtin_amdgcn_update_dpp(0, __float_as_int(x), 0x130, 0xf, 0xf, true));
}
__device__ __forceinline__ int dpp_shl1_i(int x) {
  return __builtin_amdgcn_update_dpp(0, x, 0x130, 0xf, 0xf, true);
}
#define DPPADD(v, ctrl, rmask)                                                              \
  v += __int_as_float(__builtin_amdgcn_update_dpp(0, __float_as_int(v), ctrl, rmask, 0xf, true));

#define COMPACT(BB)                                                          \
  int base = 0;                                                              \
  {                                                                          \
    cmp[lane] = 0; cmp[64 + lane] = 0; cmp[128 + lane] = 0; cmp[192 + lane] = 0; \
    _Pragma("unroll") for (int cc = 0; cc < 4; ++cc) {                       \
      const int l = cc * 64 + lane;                                          \
      const int v = (l < L_) ? targets[(BB) * L_ + l] : 0;                   \
      const unsigned long long mk = __ballot(v != 0);                        \
      const int pos = base + __popcll(mk & ((1ull << lane) - 1ull));         \
      if (v != 0) cmp[pos] = v;                                              \
      base += __popcll(mk);                                                  \
    }                                                                        \
    asm volatile("s_waitcnt lgkmcnt(0)" ::: "memory");                       \
  }

// ================== phase A: softmax + gather -> compact fp16 ==================
__global__ __launch_bounds__(256, 2) void kprob(const float* __restrict__ logits,
                                                const int* __restrict__ lens,
                                                const int* __restrict__ targets,
                                                u64x2* __restrict__ cull2,
                                                float* __restrict__ bl) {
  const int tid = threadIdx.x;
  const int wid = tid >> 6;
  const int lane = tid & 63;
  __shared__ int cmp[256];
  __shared__ __align__(16) float scr[4][8][512];  // 64 KB: per-wave 8-row exp scratch

  const int g = blockIdx.x;
  const int b = g & 63;
  const int jb = g >> 6;
  const int len = lens[b];
  const int nch = (len + 7) >> 3;  // in [219, 250] (len >= 1745)
  if (wid == 0) { COMPACT(b); }
  __syncthreads();
  const int slot = jb * 4 + wid;  // 0..63; chunks slot, slot+64, slot+128[, slot+192]

  const int4 c4 = *(const int4*)(&cmp[4 * lane]);
  const int l0 = 4 * lane;
  const bool v0 = l0 + 0 < L_, v1 = l0 + 1 < L_, v2 = l0 + 2 < L_, v3 = l0 + 3 < L_;
  const float* bbase = logits + (size_t)b * (T_ * V_);

  float4 XA[16], XB[16];

#define LOADX(BUF, C)                                                        \
  {                                                                          \
    const float* rp_ = bbase + (size_t)(C) * (8 * V_);                       \
    _Pragma("unroll") for (int r = 0; r < 8; ++r) {                          \
      X##BUF[2 * r] = *(const float4*)(rp_ + r * V_ + 4 * lane);             \
      X##BUF[2 * r + 1] = *(const float4*)(rp_ + r * V_ + 256 + 4 * lane);   \
    }                                                                        \
  }

#define PROC(BUF, C)                                                         \
  {                                                                          \
    float inv_[8], blb_[8];                                                  \
    _Pragma("unroll") for (int r = 0; r < 8; ++r) {                          \
      const float4 xe = X##BUF[2 * r], xo = X##BUF[2 * r + 1];               \
      const float e0 = __expf(xe.x), e1 = __expf(xe.y);                      \
      const float e2 = __expf(xe.z), e3 = __expf(xe.w);                      \
      const float e4 = __expf(xo.x), e5 = __expf(xo.y);                      \
      const float e6 = __expf(xo.z), e7 = __expf(xo.w);                      \
      float s = ((e0 + e1) + (e2 + e3)) + ((e4 + e5) + (e6 + e7));           \
      DPPADD(s, 0x111, 0xf); DPPADD(s, 0x112, 0xf); DPPADD(s, 0x114, 0xf);   \
      DPPADD(s, 0x118, 0xf); DPPADD(s, 0x142, 0xa); DPPADD(s, 0x143, 0xc);   \
      const float sum = __int_as_float(__builtin_amdgcn_readlane(__float_as_int(s), 63)); \
      const float iv = 32.0f / sum;  /* same x32 prescale as verified */     \
      inv_[r] = iv;                                                          \
      blb_[r] = e0 * iv;  /* blank prob; meaningful on lane 0 */             \
      float* sc_ = &scr[wid][r][0];                                          \
      *(float4*)(sc_ + 4 * lane) = make_float4(e0, e1, e2, e3);              \
      *(float4*)(sc_ + 256 + 4 * lane) = make_float4(e4, e5, e6, e7);        \
    }                                                                        \
    asm volatile("s_waitcnt lgkmcnt(0)" ::: "memory"); /* ONE wait/chunk */  \
    u64x2* outp_ = cull2 + ((size_t)(b * NCH + (C)) * 4) * 64 + lane;        \
    unsigned long long pe_ = 0;                                              \
    _Pragma("unroll") for (int r = 0; r < 8; ++r) {                          \
      const float* sc_ = &scr[wid][r][0];                                    \
      const float iv = inv_[r];                                              \
      H4U p;                                                                 \
      p.h.x = (_Float16)(v0 ? sc_[c4.x] * iv : 0.0f);                        \
      p.h.y = (_Float16)(v1 ? sc_[c4.y] * iv : 0.0f);                        \
      p.h.z = (_Float16)(v2 ? sc_[c4.z] * iv : 0.0f);                        \
      p.h.w = (_Float16)(v3 ? sc_[c4.w] * iv : 0.0f);                        \
      if (r & 1) { u64x2 w_; w_.x = pe_; w_.y = p.u; outp_[(r >> 1) * 64] = w_; } \
      else pe_ = p.u;                                                        \
    }                                                                        \
    if (lane == 0) {                                                         \
      float4* bp_ = (float4*)(bl + b * 2048 + (C) * 8);                      \
      bp_[0] = make_float4(blb_[0], blb_[1], blb_[2], blb_[3]);              \
      bp_[1] = make_float4(blb_[4], blb_[5], blb_[6], blb_[7]);              \
    }                                                                        \
  }

  // chunks: cA=slot, cB=slot+64, cC=slot+128 always < nch (191 < 219); cD guarded
  const int cA = slot, cB = slot + 64, cC = slot + 128, cD = slot + 192;
  const bool hasD = cD < nch;
  LOADX(A, cA);
  LOADX(B, cB);
  PROC(A, cA);      // while B's loads are in flight
  LOADX(A, cC);
  PROC(B, cB);      // while A's (cC) loads are in flight
  if (hasD) LOADX(B, cD);
  PROC(A, cC);
  if (hasD) PROC(B, cD);
#undef LOADX
#undef PROC
}

// ================== phase B: fwd/bwd block-float recursions ==================
__global__ __launch_bounds__(64) void krec(const int* __restrict__ lens,
                                           const int* __restrict__ targets,
                                           const u64x2* __restrict__ cull2,
                                           const float* __restrict__ bl,
                                           float* __restrict__ AF, int* __restrict__ EF,
                                           float* __restrict__ DD, int* __restrict__ EB) {
  const int lane = threadIdx.x;
  __shared__ int cmp[256];
  const int b = blockIdx.x >> 1;
  const int dirb = blockIdx.x & 1;
  const int len = lens[b];
  const int rem = len & 7;
  const int nch = (len + 7) >> 3;
  const int Cf = nch >> 1;  // fwd owns chunks [0, Cf) (all full); bwd owns [Cf, nch)
  const int Ntot = dirb ? (nch - Cf) : Cf;  // in [109,125] (len >= 1744)
  const int c0v = dirb ? (nch - 1) : 0;
  const int dstep = dirb ? -1 : 1;
#define CHK(J) (c0v + dstep * (J))

  COMPACT(b);
  const int tl = base;
  const int4 c4 = *(const int4*)(&cmp[4 * lane]);

  const int cm1 = __shfl_up(c4.w, 1);
  const float m0 = (lane > 0 && c4.x != 0 && c4.x != cm1) ? 1.0f : 0.0f;
  const float m1 = (c4.y != 0 && c4.y != c4.x) ? 1.0f : 0.0f;
  const float m2 = (c4.z != 0 && c4.z != c4.y) ? 1.0f : 0.0f;
  const float m3 = (c4.w != 0 && c4.w != c4.z) ? 1.0f : 0.0f;
  const float m0n = dpp_shl1_f(m0);

  float a0 = 0.f, a1 = 0.f, a2 = 0.f, a3 = 0.f, a4 = 0.f, a5 = 0.f, a6 = 0.f, a7 = 0.f;
  int E = 0;
  float fac = 1.0f;
  if (!dirb) {
    if (lane == 0) a0 = 1.0f;  // chunk-0 step u=0 reproduces the alpha init
  } else {
    const int st = 2 * tl;  // gamma seed; first bwd step reproduces the init
    if (lane == (st >> 3)) {
      const int e = st & 7;
      a0 = (e == 0) ? 1.0f : 0.0f; a1 = (e == 1) ? 1.0f : 0.0f;
      a2 = (e == 2) ? 1.0f : 0.0f; a3 = (e == 3) ? 1.0f : 0.0f;
      a4 = (e == 4) ? 1.0f : 0.0f; a5 = (e == 5) ? 1.0f : 0.0f;
      a6 = (e == 6) ? 1.0f : 0.0f; a7 = (e == 7) ? 1.0f : 0.0f;
    }
  }

  // 6-deep pipeline buffers (named; all indexing compile-time)
  u64x2 Qa0, Qb0, Qc0, Qd0, Qa1, Qb1, Qc1, Qd1, Qa2, Qb2, Qc2, Qd2;
  u64x2 Qa3, Qb3, Qc3, Qd3, Qa4, Qb4, Qc4, Qd4, Qa5, Qb5, Qc5, Qd5;
  float4 BLa0, BLb0, BLa1, BLb1, BLa2, BLb2, BLa3, BLb3, BLa4, BLb4, BLa5, BLb5;

#define LOADC(S, CIDX)                                                       \
  {                                                                          \
    const int c_ = (CIDX);                                                   \
    const u64x2* pp_ = cull2 + ((size_t)(b * NCH + c_) * 4) * 64 + lane;     \
    Qa##S = pp_[0]; Qb##S = pp_[64]; Qc##S = pp_[128]; Qd##S = pp_[192];     \
    const float* bf_ = bl + b * 2048 + c_ * 8;                               \
    BLa##S = *(const float4*)(bf_);                                          \
    BLb##S = *(const float4*)(bf_ + 4);                                      \
  }

#define STEP8F(S)                                                            \
  {                                                                          \
    const float blv_[8] = {BLa##S.x, BLa##S.y, BLa##S.z, BLa##S.w,           \
                           BLb##S.x, BLb##S.y, BLb##S.z, BLb##S.w};          \
    const unsigned long long qu_[8] = {Qa##S.x, Qa##S.y, Qb##S.x, Qb##S.y,   \
                                       Qc##S.x, Qc##S.y, Qd##S.x, Qd##S.y};  \
    _Pragma("unroll") for (int u = 0; u < 8; ++u) {                          \
      H4U q_; q_.u = qu_[u];                                                 \
      const float qx = (float)q_.h.x, qy = (float)q_.h.y;                    \
      const float qz = (float)q_.h.z, qw = (float)q_.h.w;                    \
      const float pbv = blv_[u];                                             \
      const float s1 = dpp_shr1_f(a7) * fac;  /* lane0 -> 0 */               \
      float n0 = (a0 + s1) * pbv;                                            \
      float n1 = fmaf(m0, s1, a0 + a1) * qx;                                 \
      float n2 = (a2 + a1) * pbv;                                            \
      float n3 = fmaf(m1, a1, a2 + a3) * qy;                                 \
      float n4 = (a4 + a3) * pbv;                                            \
      float n5 = fmaf(m2, a3, a4 + a5) * qz;                                 \
      float n6 = (a6 + a5) * pbv;                                            \
      float n7 = fmaf(m3, a5, a6 + a7) * qw;                                 \
      a0 = n0; a1 = n1; a2 = n2; a3 = n3;                                    \
      a4 = n4; a5 = n5; a6 = n6; a7 = n7;                                    \
    }                                                                        \
  }

#define STEP8B(S, UHI)                                                       \
  {                                                                          \
    const float blv_[8] = {BLa##S.x, BLa##S.y, BLa##S.z, BLa##S.w,           \
                           BLb##S.x, BLb##S.y, BLb##S.z, BLb##S.w};          \
    const unsigned long long qu_[8] = {Qa##S.x, Qa##S.y, Qb##S.x, Qb##S.y,   \
                                       Qc##S.x, Qc##S.y, Qd##S.x, Qd##S.y};  \
    _Pragma("unroll") for (int u = 7; u >= 0; --u) {                         \
      if (u <= (UHI)) {                                                      \
        H4U q_; q_.u = qu_[u];                                               \
        const float qx = (float)q_.h.x, qy = (float)q_.h.y;                  \
        const float qz = (float)q_.h.z, qw = (float)q_.h.w;                  \
        const float pbv = blv_[u];                                           \
        const float sa = dpp_shl1_f(a0) * fac;  /* lane63 -> 0 */            \
        const float sb = dpp_shl1_f(a1) * fac;                               \
        float n0 = (a0 + a1) * pbv;                                          \
        float n1 = fmaf(m1, a3, a1 + a2) * qx;                               \
        float n2 = (a2 + a3) * pbv;                                          \
        float n3 = fmaf(m2, a5, a3 + a4) * qy;                               \
        float n4 = (a4 + a5) * pbv;                                          \
        float n5 = fmaf(m3, a7, a5 + a6) * qz;                               \
        float n6 = (a6 + a7) * pbv;                                          \
        float n7 = fmaf(m0n, sb, a7 + sa) * qw;                              \
        a0 = n0; a1 = n1; a2 = n2; a3 = n3;                                  \
        a4 = n4; a5 = n5; a6 = n6; a7 = n7;                                  \
      }                                                                      \
    }                                                                        \
  }

#define RENORM_COMMON                                                        \
    const float mx = fmaxf(fmaxf(fmaxf(a0, a1), fmaxf(a2, a3)),              \
                           fmaxf(fmaxf(a4, a5), fmaxf(a6, a7)));             \
    const bool dead = (mx == 0.0f);                                          \
    int e_ = (int)((__float_as_uint(mx) >> 23) & 0xff) - 127;                \
    if (dead) e_ = 0;                                                        \
    const float sc_ = __int_as_float((unsigned)(127 - e_) << 23);            \
    a0 *= sc_; a1 *= sc_; a2 *= sc_; a3 *= sc_;                              \
    a4 *= sc_; a5 *= sc_; a6 *= sc_; a7 *= sc_;                              \
    const int En_ = E + e_;

#define RENORMF                                                              \
  {                                                                          \
    RENORM_COMMON                                                            \
    const int EnP_ = dpp_shr1_i(En_);                                        \
    E = dead ? EnP_ : En_;                                                   \
    const int Ep_ = dpp_shr1_i(E);                                           \
    const int d_ = Ep_ - E;                                                  \
    int dc_ = d_ < -126 ? -126 : (d_ > 126 ? 126 : d_);                      \
    fac = (d_ < -126) ? 0.0f : __int_as_float((unsigned)(dc_ + 127) << 23);  \
  }

#define RENORMB                                                              \
  {                                                                          \
    RENORM_COMMON                                                            \
    const int EnP_ = dpp_shl1_i(En_);                                        \
    E = dead ? EnP_ : En_;                                                   \
    const int Ep_ = dpp_shl1_i(E);                                           \
    const int d_ = Ep_ - E;                                                  \
    int dc_ = d_ < -126 ? -126 : (d_ > 126 ? 126 : d_);                      \
    fac = (d_ < -126) ? 0.0f : __int_as_float((unsigned)(dc_ + 127) << 23);  \
  }

  // prologue: chunks 0..5 into buffers 0..5 (Ntot >= 109 >> 12)
  LOADC(0, CHK(0)); LOADC(1, CHK(1)); LOADC(2, CHK(2));
  LOADC(3, CHK(3)); LOADC(4, CHK(4)); LOADC(5, CHK(5));
  int i = 0;

  if (!dirb) {
    // first group (straight-line), then 6-chunk straight-line main loop
    STEP8F(0); LOADC(0, CHK(6));  RENORMF;
    STEP8F(1); LOADC(1, CHK(7));  RENORMF;
    STEP8F(2); LOADC(2, CHK(8));  RENORMF;
    STEP8F(3); LOADC(3, CHK(9));  RENORMF;
    STEP8F(4); LOADC(4, CHK(10)); RENORMF;
    STEP8F(5); LOADC(5, CHK(11)); RENORMF;
    i = 6;
    while (i + 12 <= Ntot) {
      STEP8F(0); LOADC(0, CHK(i + 6));  RENORMF;
      STEP8F(1); LOADC(1, CHK(i + 7));  RENORMF;
      STEP8F(2); LOADC(2, CHK(i + 8));  RENORMF;
      STEP8F(3); LOADC(3, CHK(i + 9));  RENORMF;
      STEP8F(4); LOADC(4, CHK(i + 10)); RENORMF;
      STEP8F(5); LOADC(5, CHK(i + 11)); RENORMF;
      i += 6;
    }
    const int r2 = Ntot - i;  // in [6,12)
    for (int k = 0; k < r2; ++k) {
      const int nx = i + k + 6;
      const bool pf = nx < Ntot;
      switch (k % 6) {
        case 0: STEP8F(0); RENORMF; if (pf) LOADC(0, CHK(nx)); break;
        case 1: STEP8F(1); RENORMF; if (pf) LOADC(1, CHK(nx)); break;
        case 2: STEP8F(2); RENORMF; if (pf) LOADC(2, CHK(nx)); break;
        case 3: STEP8F(3); RENORMF; if (pf) LOADC(3, CHK(nx)); break;
        case 4: STEP8F(4); RENORMF; if (pf) LOADC(4, CHK(nx)); break;
        default: STEP8F(5); RENORMF; if (pf) LOADC(5, CHK(nx)); break;
      }
    }
    *(float4*)(AF + b * 512 + lane * 8) = make_float4(a0, a1, a2, a3);
    *(float4*)(AF + b * 512 + lane * 8 + 4) = make_float4(a4, a5, a6, a7);
    EF[b * 64 + lane] = E;
  } else {
    const int uh0 = rem ? (rem - 1) : 7;  // masked tail is the first consumed chunk
    STEP8B(0, uh0); LOADC(0, CHK(6));  RENORMB;
    STEP8B(1, 7);   LOADC(1, CHK(7));  RENORMB;
    STEP8B(2, 7);   LOADC(2, CHK(8));  RENORMB;
    STEP8B(3, 7);   LOADC(3, CHK(9));  RENORMB;
    STEP8B(4, 7);   LOADC(4, CHK(10)); RENORMB;
    STEP8B(5, 7);   LOADC(5, CHK(11)); RENORMB;
    i = 6;
    while (i + 12 <= Ntot) {
      STEP8B(0, 7); LOADC(0, CHK(i + 6));  RENORMB;
      STEP8B(1, 7); LOADC(1, CHK(i + 7));  RENORMB;
      STEP8B(2, 7); LOADC(2, CHK(i + 8));  RENORMB;
      STEP8B(3, 7); LOADC(3, CHK(i + 9));  RENORMB;
      STEP8B(4, 7); LOADC(4, CHK(i + 10)); RENORMB;
      STEP8B(5, 7); LOADC(5, CHK(i + 11)); RENORMB;
      i += 6;
    }
    const int r2 = Ntot - i;  // in [6,12)
    for (int k = 0; k < r2; ++k) {
      const int nx = i + k + 6;
      const bool pf = nx < Ntot;
      switch (k % 6) {
        case 0: STEP8B(0, 7); RENORMB; if (pf) LOADC(0, CHK(nx)); break;
        case 1: STEP8B(1, 7); RENORMB; if (pf) LOADC(1, CHK(nx)); break;
        case 2: STEP8B(2, 7); RENORMB; if (pf) LOADC(2, CHK(nx)); break;
        case 3: STEP8B(3, 7); RENORMB; if (pf) LOADC(3, CHK(nx)); break;
        case 4: STEP8B(4, 7); RENORMB; if (pf) LOADC(4, CHK(nx)); break;
        default: STEP8B(5, 7); RENORMB; if (pf) LOADC(5, CHK(nx)); break;
      }
    }
    // delta = one emission-less backward step of gamma_{8Cf}
    const float sa = dpp_shl1_f(a0) * fac;
    const float sb = dpp_shl1_f(a1) * fac;
    const float d0 = a0 + a1;
    const float d1 = fmaf(m1, a3, a1 + a2);
    const float d2 = a2 + a3;
    const float d3 = fmaf(m2, a5, a3 + a4);
    const float d4 = a4 + a5;
    const float d5 = fmaf(m3, a7, a5 + a6);
    const float d6 = a6 + a7;
    const float d7 = fmaf(m0n, sb, a7 + sa);
    *(float4*)(DD + b * 512 + lane * 8) = make_float4(d0, d1, d2, d3);
    *(float4*)(DD + b * 512 + lane * 8 + 4) = make_float4(d4, d5, d6, d7);
    EB[b * 64 + lane] = E;
  }
#undef LOADC
#undef STEP8F
#undef STEP8B
#undef RENORM_COMMON
#undef RENORMF
#undef RENORMB
#undef CHK
}

// ---- splice + final sum: out = -sum_b log( sum_s alpha[s]*delta[s] ) + len*ln(32) ----
__global__ __launch_bounds__(512) void kcomb(const int* __restrict__ lens,
                                             const float* __restrict__ AF,
                                             const int* __restrict__ EF,
                                             const float* __restrict__ DD,
                                             const int* __restrict__ EB,
                                             float* __restrict__ out) {
  const int wid = threadIdx.x >> 6;
  const int lane = threadIdx.x & 63;
  __shared__ float part[8];
  float acc = 0.0f;
#pragma unroll
  for (int q = 0; q < 8; ++q) {
    const int b = wid * 8 + q;
    const float4 f0 = *(const float4*)(AF + b * 512 + lane * 8);
    const float4 f1 = *(const float4*)(AF + b * 512 + lane * 8 + 4);
    const float4 g0 = *(const float4*)(DD + b * 512 + lane * 8);
    const float4 g1 = *(const float4*)(DD + b * 512 + lane * 8 + 4);
    const float dot = ((f0.x * g0.x + f0.y * g0.y) + (f0.z * g0.z + f0.w * g0.w)) +
                      ((f1.x * g1.x + f1.y * g1.y) + (f1.z * g1.z + f1.w * g1.w));
    const int Es = EF[b * 64 + lane] + EB[b * 64 + lane];
    const bool z = (dot == 0.0f);
    int Ek = z ? (-(1 << 28)) : Es;
#pragma unroll
    for (int off = 32; off; off >>= 1) {
      const int o = __shfl_xor(Ek, off);
      Ek = o > Ek ? o : Ek;
    }
    float v = z ? 0.0f : ldexpf(dot, Es - Ek);
#pragma unroll
    for (int off = 32; off; off >>= 1) v += __shfl_xor(v, off);
    const float ll = __logf(v) + (float)Ek * 0.69314718056f - (float)lens[b] * 3.46573590280f;
    acc -= ll;
  }
  if (lane == 0) part[wid] = acc;
  __syncthreads();
  if (threadIdx.x == 0) {
    float s = ((part[0] + part[1]) + (part[2] + part[3])) +
              ((part[4] + part[5]) + (part[6] + part[7]));
    out[0] = s;
  }
}

extern "C" void kernel_launch(void* const* d_in, const int* in_sizes, int n_in,
                              void* d_out, int out_size, void* d_ws, size_t ws_size,
                              hipStream_t stream) {
  const float* logits = (const float*)d_in[0];     // [B,T,V] fp32 — read-only
  const int* input_lengths = (const int*)d_in[1];  // [B]
  const int* targets = (const int*)d_in[2];        // [B,L]
  float* out = (float*)d_out;                      // [1]
  // ws layout (bytes): compact fp16 pairs [B][250][4][64] x16B = 65,536,000;
  // blank f32 [B][2048] = 524,288; (gap); AF/EF/DD/EB.
  u64x2* cull2 = (u64x2*)d_ws;
  float* bl = (float*)((char*)d_ws + 65536000);
  float* AF = (float*)((char*)d_ws + 66125824);
  int* EF = (int*)((char*)d_ws + 66256896);
  float* DD = (float*)((char*)d_ws + 66273280);
  int* EB = (int*)((char*)d_ws + 66404352);
  (void)in_sizes; (void)n_in; (void)out_size; (void)ws_size;

  kprob<<<B_ * NJB, 256, 0, stream>>>(logits, input_lengths, targets, cull2, bl);
  krec<<<2 * B_, 64, 0, stream>>>(input_lengths, targets, cull2, bl, AF, EF, DD, EB);
  kcomb<<<1, 512, 0, stream>>>(input_lengths, AF, EF, DD, EB, out);
}